// Round 1
// baseline (634.747 us; speedup 1.0000x reference)
//
#include <hip/hip_runtime.h>
#include <stdint.h>

#define N_NODES 100000
#define N_EDGES 25000
#define NNZ_    800000
#define D       256

// ---------------- CSR build ----------------

__global__ void hist_kernel(const int* __restrict__ V, const int* __restrict__ E,
                            int* __restrict__ cntE, int* __restrict__ cntV, int nnz) {
    int i = blockIdx.x * blockDim.x + threadIdx.x;
    if (i < nnz) {
        atomicAdd(&cntE[E[i]], 1);
        atomicAdd(&cntV[V[i]], 1);
    }
}

// single-block exclusive scan; out has n+1 entries (out[n] = total)
__global__ void __launch_bounds__(1024) scan_kernel(const int* __restrict__ in,
                                                    int* __restrict__ out, int n) {
    const int T = 1024;
    int tid = threadIdx.x;
    int per = (n + T - 1) / T;
    int start = tid * per;
    int end = min(start + per, n);
    int s = 0;
    for (int i = start; i < end; ++i) s += in[i];
    __shared__ int sh[T];
    sh[tid] = s;
    __syncthreads();
    for (int off = 1; off < T; off <<= 1) {
        int v = (tid >= off) ? sh[tid - off] : 0;
        __syncthreads();
        sh[tid] += v;
        __syncthreads();
    }
    int excl = (tid == 0) ? 0 : sh[tid - 1];
    for (int i = start; i < end; ++i) { out[i] = excl; excl += in[i]; }
    if (tid == T - 1) out[n] = excl;
}

__global__ void fill_kernel(const int* __restrict__ V, const int* __restrict__ E,
                            const int* __restrict__ offE, const int* __restrict__ offV,
                            int* __restrict__ curE, int* __restrict__ curV,
                            int* __restrict__ adjE, int* __restrict__ adjV, int nnz) {
    int i = blockIdx.x * blockDim.x + threadIdx.x;
    if (i < nnz) {
        int e = E[i], v = V[i];
        int pe = offE[e] + atomicAdd(&curE[e], 1);
        adjE[pe] = v;
        int pv = offV[v] + atomicAdd(&curV[v], 1);
        adjV[pv] = e;
    }
}

// ---------------- phase 1: edge aggregation (one wave per edge) ----------------

__global__ void edge_agg(const float* __restrict__ input, const int* __restrict__ adjE,
                         const int* __restrict__ offE, const float* __restrict__ degE,
                         float* __restrict__ Ye) {
    int gid = blockIdx.x * blockDim.x + threadIdx.x;
    int edge = gid >> 6;
    int lane = gid & 63;
    if (edge >= N_EDGES) return;
    int b = offE[edge], e = offE[edge + 1];
    float4 acc = {0.f, 0.f, 0.f, 0.f};
    for (int i = b; i < e; ++i) {
        int v = adjE[i];
        float4 x = *reinterpret_cast<const float4*>(input + (size_t)v * D + lane * 4);
        acc.x += x.x; acc.y += x.y; acc.z += x.z; acc.w += x.w;
    }
    int cnt = e - b;
    float s = degE[edge] / (float)(cnt > 1 ? cnt : 1);
    acc.x *= s; acc.y *= s; acc.z *= s; acc.w *= s;
    *reinterpret_cast<float4*>(Ye + (size_t)edge * D + lane * 4) = acc;
}

// ---------------- phase 2: fp32 GEMM  Ze[M,256] = Ye[M,256] @ W[256,256] ----------------

#define BM 64
#define BN 64
#define BK 16

__global__ void __launch_bounds__(256) gemm_kernel(const float* __restrict__ A,
                                                   const float* __restrict__ B,
                                                   float* __restrict__ C, int M) {
    __shared__ float As[BK][BM];
    __shared__ float Bs[BK][BN];
    int t  = threadIdx.x;
    int tx = t & 15, ty = t >> 4;           // 16x16 threads, 4x4 micro-tile each
    int m0 = blockIdx.x * BM, n0 = blockIdx.y * BN;
    float acc[4][4] = {};
    int am = t >> 2;                        // 0..63 (row of A tile)
    int ak = (t & 3) * 4;                   // k sub-offset
    int bk = t >> 4;                        // 0..15 (row of B tile)
    int bn = (t & 15) * 4;                  // col sub-offset
    for (int k0 = 0; k0 < D; k0 += BK) {
        float4 a4 = {0.f, 0.f, 0.f, 0.f};
        int gm = m0 + am;
        if (gm < M) a4 = *reinterpret_cast<const float4*>(A + (size_t)gm * D + k0 + ak);
        As[ak + 0][am] = a4.x; As[ak + 1][am] = a4.y;
        As[ak + 2][am] = a4.z; As[ak + 3][am] = a4.w;
        *reinterpret_cast<float4*>(&Bs[bk][bn]) =
            *reinterpret_cast<const float4*>(B + (size_t)(k0 + bk) * D + n0 + bn);
        __syncthreads();
#pragma unroll
        for (int kk = 0; kk < BK; ++kk) {
            float4 a4v = *reinterpret_cast<const float4*>(&As[kk][ty * 4]);
            float4 b4v = *reinterpret_cast<const float4*>(&Bs[kk][tx * 4]);
            float a[4] = {a4v.x, a4v.y, a4v.z, a4v.w};
            float b[4] = {b4v.x, b4v.y, b4v.z, b4v.w};
#pragma unroll
            for (int i = 0; i < 4; ++i)
#pragma unroll
                for (int j = 0; j < 4; ++j)
                    acc[i][j] += a[i] * b[j];
        }
        __syncthreads();
    }
#pragma unroll
    for (int i = 0; i < 4; ++i) {
        int gm = m0 + ty * 4 + i;
        if (gm < M) {
            float4 c4 = {acc[i][0], acc[i][1], acc[i][2], acc[i][3]};
            *reinterpret_cast<float4*>(C + (size_t)gm * D + n0 + tx * 4) = c4;
        }
    }
}

// ---------------- phase 3: node aggregation (one wave per node) ----------------

__global__ void node_agg(const float* __restrict__ Ze, const int* __restrict__ adjV,
                         const int* __restrict__ offV, const float* __restrict__ degV,
                         const float* __restrict__ bias, float* __restrict__ out) {
    int gid = blockIdx.x * blockDim.x + threadIdx.x;
    int node = gid >> 6;
    int lane = gid & 63;
    if (node >= N_NODES) return;
    int b = offV[node], e = offV[node + 1];
    float4 acc = {0.f, 0.f, 0.f, 0.f};
    for (int i = b; i < e; ++i) {
        int ed = adjV[i];
        float4 z = *reinterpret_cast<const float4*>(Ze + (size_t)ed * D + lane * 4);
        acc.x += z.x; acc.y += z.y; acc.z += z.z; acc.w += z.w;
    }
    float dv = degV[node];
    float4 b4 = *reinterpret_cast<const float4*>(bias + lane * 4);
    float4 o = {acc.x * dv + b4.x, acc.y * dv + b4.y,
                acc.z * dv + b4.z, acc.w * dv + b4.w};
    *reinterpret_cast<float4*>(out + (size_t)node * D + lane * 4) = o;
}

// ---------------- launch ----------------

extern "C" void kernel_launch(void* const* d_in, const int* in_sizes, int n_in,
                              void* d_out, int out_size, void* d_ws, size_t ws_size,
                              hipStream_t stream) {
    const float* input  = (const float*)d_in[0];
    const int*   V      = (const int*)d_in[1];
    const int*   E      = (const int*)d_in[2];
    const float* degV   = (const float*)d_in[3];
    const float* degE   = (const float*)d_in[4];
    const float* weight = (const float*)d_in[5];
    const float* bias   = (const float*)d_in[6];
    float* out = (float*)d_out;

    int* cntE = (int*)d_ws;                 // N_EDGES
    int* cntV = cntE + N_EDGES;             // N_NODES
    int* curE = cntV + N_NODES;             // N_EDGES
    int* curV = curE + N_EDGES;             // N_NODES
    int* offE = curV + N_NODES;             // N_EDGES+1
    int* offV = offE + (N_EDGES + 1);       // N_NODES+1
    int* adjE = offV + (N_NODES + 1);       // NNZ
    int* adjV = adjE + NNZ_;                // NNZ
    uintptr_t p = (uintptr_t)(adjV + NNZ_);
    p = (p + 255) & ~(uintptr_t)255;
    float* Ye = (float*)p;                  // N_EDGES*D
    float* Ze = Ye + (size_t)N_EDGES * D;   // N_EDGES*D

    // zero the four counter arrays (contiguous)
    hipMemsetAsync(cntE, 0, (size_t)(2 * (N_EDGES + N_NODES)) * sizeof(int), stream);

    hist_kernel<<<(NNZ_ + 255) / 256, 256, 0, stream>>>(V, E, cntE, cntV, NNZ_);
    scan_kernel<<<1, 1024, 0, stream>>>(cntE, offE, N_EDGES);
    scan_kernel<<<1, 1024, 0, stream>>>(cntV, offV, N_NODES);
    fill_kernel<<<(NNZ_ + 255) / 256, 256, 0, stream>>>(V, E, offE, offV, curE, curV,
                                                        adjE, adjV, NNZ_);

    edge_agg<<<(N_EDGES * 64 + 255) / 256, 256, 0, stream>>>(input, adjE, offE, degE, Ye);

    dim3 g((N_EDGES + BM - 1) / BM, D / BN);
    gemm_kernel<<<g, 256, 0, stream>>>(Ye, weight, Ze, N_EDGES);

    node_agg<<<(N_NODES * 64 + 255) / 256, 256, 0, stream>>>(Ze, adjV, offV, degV, bias, out);
}

// Round 2
// 457.029 us; speedup vs baseline: 1.3889x; 1.3889x over previous
//
#include <hip/hip_runtime.h>
#include <stdint.h>

#define N_NODES 100000
#define N_EDGES 25000
#define NNZ_    800000
#define D       256
#define NTOT    (N_EDGES + N_NODES)   // combined counter array length
#define SB      1024                  // elements per scan block
#define NBLK    ((NTOT + SB) / SB)    // covers NTOT+1 positions (off[n] write)

// ---------------- CSR build ----------------

__global__ void hist_kernel(const int* __restrict__ V, const int* __restrict__ E,
                            int* __restrict__ cntC, int nnz) {
    int i = blockIdx.x * blockDim.x + threadIdx.x;
    if (i < nnz) {
        atomicAdd(&cntC[E[i]], 1);
        atomicAdd(&cntC[N_EDGES + V[i]], 1);
    }
}

// K1: per-block sums of 1024 elements (256 thr x int4)
__global__ void __launch_bounds__(256) scan_bsum(const int* __restrict__ in,
                                                 int* __restrict__ bsum, int n) {
    __shared__ int sh[256];
    int b = blockIdx.x, t = threadIdx.x;
    int base = b * SB + t * 4;
    int s = 0;
    if (base + 4 <= n) {
        int4 v = *reinterpret_cast<const int4*>(in + base);
        s = v.x + v.y + v.z + v.w;
    } else {
        for (int k = 0; k < 4; ++k)
            if (base + k < n) s += in[base + k];
    }
    sh[t] = s;
    __syncthreads();
    for (int off = 128; off > 0; off >>= 1) {
        if (t < off) sh[t] += sh[t + off];
        __syncthreads();
    }
    if (t == 0) bsum[b] = sh[0];
}

// K2: exclusive scan of block sums (single small block; NBLK <= 128)
__global__ void __launch_bounds__(128) scan_boff(int* __restrict__ bsum, int nb) {
    __shared__ int sh[128];
    int t = threadIdx.x;
    int v = (t < nb) ? bsum[t] : 0;
    sh[t] = v;
    __syncthreads();
    for (int off = 1; off < 128; off <<= 1) {
        int u = (t >= off) ? sh[t - off] : 0;
        __syncthreads();
        sh[t] += u;
        __syncthreads();
    }
    if (t < nb) bsum[t] = sh[t] - v;  // exclusive
}

// K3: full exclusive scan -> off[0..n] (off[n] = total)
__global__ void __launch_bounds__(256) scan_write(const int* __restrict__ in,
                                                  const int* __restrict__ bsum,
                                                  int* __restrict__ off, int n) {
    __shared__ int sh[256];
    int b = blockIdx.x, t = threadIdx.x;
    int base = b * SB + t * 4;
    int v0 = 0, v1 = 0, v2 = 0, v3 = 0;
    if (base + 4 <= n) {
        int4 v = *reinterpret_cast<const int4*>(in + base);
        v0 = v.x; v1 = v.y; v2 = v.z; v3 = v.w;
    } else {
        if (base + 0 < n) v0 = in[base + 0];
        if (base + 1 < n) v1 = in[base + 1];
        if (base + 2 < n) v2 = in[base + 2];
        if (base + 3 < n) v3 = in[base + 3];
    }
    int s = v0 + v1 + v2 + v3;
    sh[t] = s;
    __syncthreads();
    for (int o = 1; o < 256; o <<= 1) {     // inclusive Hillis-Steele
        int u = (t >= o) ? sh[t - o] : 0;
        __syncthreads();
        sh[t] += u;
        __syncthreads();
    }
    int excl = bsum[b] + sh[t] - s;
    if (base + 0 <= n) off[base + 0] = excl; excl += v0;
    if (base + 1 <= n) off[base + 1] = excl; excl += v1;
    if (base + 2 <= n) off[base + 2] = excl; excl += v2;
    if (base + 3 <= n) off[base + 3] = excl;
}

__global__ void fill_kernel(const int* __restrict__ V, const int* __restrict__ E,
                            const int* __restrict__ offC, int* __restrict__ curC,
                            int* __restrict__ adjAll, int nnz) {
    int i = blockIdx.x * blockDim.x + threadIdx.x;
    if (i < nnz) {
        int e = E[i], v = V[i];
        int pe = offC[e] + atomicAdd(&curC[e], 1);
        adjAll[pe] = v;
        int pv = offC[N_EDGES + v] + atomicAdd(&curC[N_EDGES + v], 1);
        adjAll[pv] = e;
    }
}

// ---------------- phase 1: edge aggregation (one wave per edge) ----------------

__global__ void edge_agg(const float* __restrict__ input, const int* __restrict__ adjAll,
                         const int* __restrict__ offC, const float* __restrict__ degE,
                         float* __restrict__ Ye) {
    int gid = blockIdx.x * blockDim.x + threadIdx.x;
    int edge = gid >> 6;
    int lane = gid & 63;
    if (edge >= N_EDGES) return;
    int b = offC[edge], e = offC[edge + 1];
    float4 acc = {0.f, 0.f, 0.f, 0.f};
    for (int i = b; i < e; ++i) {
        int v = adjAll[i];
        float4 x = *reinterpret_cast<const float4*>(input + (size_t)v * D + lane * 4);
        acc.x += x.x; acc.y += x.y; acc.z += x.z; acc.w += x.w;
    }
    int cnt = e - b;
    float s = degE[edge] / (float)(cnt > 1 ? cnt : 1);
    acc.x *= s; acc.y *= s; acc.z *= s; acc.w *= s;
    *reinterpret_cast<float4*>(Ye + (size_t)edge * D + lane * 4) = acc;
}

// ---------------- phase 2: fp32 GEMM  Ze[M,256] = Ye[M,256] @ W[256,256] ----------------

#define BM 64
#define BN 64
#define BK 16

__global__ void __launch_bounds__(256) gemm_kernel(const float* __restrict__ A,
                                                   const float* __restrict__ B,
                                                   float* __restrict__ C, int M) {
    __shared__ float As[BK][BM];
    __shared__ float Bs[BK][BN];
    int t  = threadIdx.x;
    int tx = t & 15, ty = t >> 4;
    int m0 = blockIdx.x * BM, n0 = blockIdx.y * BN;
    float acc[4][4] = {};
    int am = t >> 2;
    int ak = (t & 3) * 4;
    int bk = t >> 4;
    int bn = (t & 15) * 4;
    for (int k0 = 0; k0 < D; k0 += BK) {
        float4 a4 = {0.f, 0.f, 0.f, 0.f};
        int gm = m0 + am;
        if (gm < M) a4 = *reinterpret_cast<const float4*>(A + (size_t)gm * D + k0 + ak);
        As[ak + 0][am] = a4.x; As[ak + 1][am] = a4.y;
        As[ak + 2][am] = a4.z; As[ak + 3][am] = a4.w;
        *reinterpret_cast<float4*>(&Bs[bk][bn]) =
            *reinterpret_cast<const float4*>(B + (size_t)(k0 + bk) * D + n0 + bn);
        __syncthreads();
#pragma unroll
        for (int kk = 0; kk < BK; ++kk) {
            float4 a4v = *reinterpret_cast<const float4*>(&As[kk][ty * 4]);
            float4 b4v = *reinterpret_cast<const float4*>(&Bs[kk][tx * 4]);
            float a[4] = {a4v.x, a4v.y, a4v.z, a4v.w};
            float bb[4] = {b4v.x, b4v.y, b4v.z, b4v.w};
#pragma unroll
            for (int i = 0; i < 4; ++i)
#pragma unroll
                for (int j = 0; j < 4; ++j)
                    acc[i][j] += a[i] * bb[j];
        }
        __syncthreads();
    }
#pragma unroll
    for (int i = 0; i < 4; ++i) {
        int gm = m0 + ty * 4 + i;
        if (gm < M) {
            float4 c4 = {acc[i][0], acc[i][1], acc[i][2], acc[i][3]};
            *reinterpret_cast<float4*>(C + (size_t)gm * D + n0 + tx * 4) = c4;
        }
    }
}

// ---------------- phase 3: node aggregation (one wave per node) ----------------

__global__ void node_agg(const float* __restrict__ Ze, const int* __restrict__ adjAll,
                         const int* __restrict__ offC, const float* __restrict__ degV,
                         const float* __restrict__ bias, float* __restrict__ out) {
    int gid = blockIdx.x * blockDim.x + threadIdx.x;
    int node = gid >> 6;
    int lane = gid & 63;
    if (node >= N_NODES) return;
    int b = offC[N_EDGES + node], e = offC[N_EDGES + node + 1];
    float4 acc = {0.f, 0.f, 0.f, 0.f};
    for (int i = b; i < e; ++i) {
        int ed = adjAll[i];
        float4 z = *reinterpret_cast<const float4*>(Ze + (size_t)ed * D + lane * 4);
        acc.x += z.x; acc.y += z.y; acc.z += z.z; acc.w += z.w;
    }
    float dv = degV[node];
    float4 b4 = *reinterpret_cast<const float4*>(bias + lane * 4);
    float4 o = {acc.x * dv + b4.x, acc.y * dv + b4.y,
                acc.z * dv + b4.z, acc.w * dv + b4.w};
    *reinterpret_cast<float4*>(out + (size_t)node * D + lane * 4) = o;
}

// ---------------- launch ----------------

extern "C" void kernel_launch(void* const* d_in, const int* in_sizes, int n_in,
                              void* d_out, int out_size, void* d_ws, size_t ws_size,
                              hipStream_t stream) {
    const float* input  = (const float*)d_in[0];
    const int*   V      = (const int*)d_in[1];
    const int*   E      = (const int*)d_in[2];
    const float* degV   = (const float*)d_in[3];
    const float* degE   = (const float*)d_in[4];
    const float* weight = (const float*)d_in[5];
    const float* bias   = (const float*)d_in[6];
    float* out = (float*)d_out;

    int* cntC   = (int*)d_ws;               // NTOT
    int* curC   = cntC + NTOT;              // NTOT
    int* offC   = curC + NTOT;              // NTOT+1
    int* bsum   = offC + (NTOT + 1);        // 128
    int* adjAll = bsum + 128;               // 2*NNZ
    uintptr_t p = (uintptr_t)(adjAll + 2 * NNZ_);
    p = (p + 255) & ~(uintptr_t)255;
    float* Ye = (float*)p;                  // N_EDGES*D
    float* Ze = Ye + (size_t)N_EDGES * D;   // N_EDGES*D

    hipMemsetAsync(cntC, 0, (size_t)(2 * NTOT) * sizeof(int), stream);

    hist_kernel<<<(NNZ_ + 255) / 256, 256, 0, stream>>>(V, E, cntC, NNZ_);

    scan_bsum<<<NBLK, 256, 0, stream>>>(cntC, bsum, NTOT);
    scan_boff<<<1, 128, 0, stream>>>(bsum, NBLK);
    scan_write<<<NBLK, 256, 0, stream>>>(cntC, bsum, offC, NTOT);

    fill_kernel<<<(NNZ_ + 255) / 256, 256, 0, stream>>>(V, E, offC, curC, adjAll, NNZ_);

    edge_agg<<<(N_EDGES * 64 + 255) / 256, 256, 0, stream>>>(input, adjAll, offC, degE, Ye);

    dim3 g((N_EDGES + BM - 1) / BM, D / BN);
    gemm_kernel<<<g, 256, 0, stream>>>(Ye, weight, Ze, N_EDGES);

    node_agg<<<(N_NODES * 64 + 255) / 256, 256, 0, stream>>>(Ze, adjAll, offC, degV, bias, out);
}

// Round 3
// 451.889 us; speedup vs baseline: 1.4047x; 1.0114x over previous
//
#include <hip/hip_runtime.h>
#include <stdint.h>

#define N_NODES 100000
#define N_EDGES 25000
#define NNZ_    800000
#define D       256
#define NTOT    (N_EDGES + N_NODES)
#define SB      1024
#define NBLK    ((NTOT + SB) / SB)
#define MP      25024                 // N_EDGES padded to 64

typedef short  short8  __attribute__((ext_vector_type(8)));
typedef float  f32x4   __attribute__((ext_vector_type(4)));
typedef ushort ushortx8 __attribute__((ext_vector_type(8)));
typedef ushort ushortx4 __attribute__((ext_vector_type(4)));

__device__ __forceinline__ ushort f2bf(float f) {
    uint32_t u = __float_as_uint(f);
    uint32_t r = u + 0x7fffu + ((u >> 16) & 1u);
    return (ushort)(r >> 16);
}
__device__ __forceinline__ float bf2f(ushort u) {
    return __uint_as_float(((uint32_t)u) << 16);
}

// ---------------- dtype conversion ----------------

__global__ void __launch_bounds__(256) cvt_in(const float* __restrict__ in,
                                              ushort* __restrict__ ob, int n8) {
    int i = blockIdx.x * blockDim.x + threadIdx.x;
    if (i >= n8) return;
    const float4* p = reinterpret_cast<const float4*>(in) + (size_t)i * 2;
    float4 a = p[0], b = p[1];
    ushortx8 o;
    o[0] = f2bf(a.x); o[1] = f2bf(a.y); o[2] = f2bf(a.z); o[3] = f2bf(a.w);
    o[4] = f2bf(b.x); o[5] = f2bf(b.y); o[6] = f2bf(b.z); o[7] = f2bf(b.w);
    *(reinterpret_cast<ushortx8*>(ob) + i) = o;
}

// W[k][n] fp32 -> WT[n][k] bf16 (256x256)
__global__ void __launch_bounds__(256) cvt_wt(const float* __restrict__ W,
                                              ushort* __restrict__ WT) {
    int t = blockIdx.x * blockDim.x + threadIdx.x;
    int n = t >> 8, k = t & 255;
    WT[(size_t)n * 256 + k] = f2bf(W[(size_t)k * 256 + n]);
}

// ---------------- CSR build ----------------

__global__ void hist_kernel(const int* __restrict__ V, const int* __restrict__ E,
                            int* __restrict__ cntC, int nnz) {
    int i = blockIdx.x * blockDim.x + threadIdx.x;
    if (i < nnz) {
        atomicAdd(&cntC[E[i]], 1);
        atomicAdd(&cntC[N_EDGES + V[i]], 1);
    }
}

__global__ void __launch_bounds__(256) scan_bsum(const int* __restrict__ in,
                                                 int* __restrict__ bsum, int n) {
    __shared__ int sh[256];
    int b = blockIdx.x, t = threadIdx.x;
    int base = b * SB + t * 4;
    int s = 0;
    if (base + 4 <= n) {
        int4 v = *reinterpret_cast<const int4*>(in + base);
        s = v.x + v.y + v.z + v.w;
    } else {
        for (int k = 0; k < 4; ++k)
            if (base + k < n) s += in[base + k];
    }
    sh[t] = s;
    __syncthreads();
    for (int off = 128; off > 0; off >>= 1) {
        if (t < off) sh[t] += sh[t + off];
        __syncthreads();
    }
    if (t == 0) bsum[b] = sh[0];
}

__global__ void __launch_bounds__(128) scan_boff(int* __restrict__ bsum, int nb) {
    __shared__ int sh[128];
    int t = threadIdx.x;
    int v = (t < nb) ? bsum[t] : 0;
    sh[t] = v;
    __syncthreads();
    for (int off = 1; off < 128; off <<= 1) {
        int u = (t >= off) ? sh[t - off] : 0;
        __syncthreads();
        sh[t] += u;
        __syncthreads();
    }
    if (t < nb) bsum[t] = sh[t] - v;
}

__global__ void __launch_bounds__(256) scan_write(const int* __restrict__ in,
                                                  const int* __restrict__ bsum,
                                                  int* __restrict__ off, int n) {
    __shared__ int sh[256];
    int b = blockIdx.x, t = threadIdx.x;
    int base = b * SB + t * 4;
    int v0 = 0, v1 = 0, v2 = 0, v3 = 0;
    if (base + 4 <= n) {
        int4 v = *reinterpret_cast<const int4*>(in + base);
        v0 = v.x; v1 = v.y; v2 = v.z; v3 = v.w;
    } else {
        if (base + 0 < n) v0 = in[base + 0];
        if (base + 1 < n) v1 = in[base + 1];
        if (base + 2 < n) v2 = in[base + 2];
        if (base + 3 < n) v3 = in[base + 3];
    }
    int s = v0 + v1 + v2 + v3;
    sh[t] = s;
    __syncthreads();
    for (int o = 1; o < 256; o <<= 1) {
        int u = (t >= o) ? sh[t - o] : 0;
        __syncthreads();
        sh[t] += u;
        __syncthreads();
    }
    int excl = bsum[b] + sh[t] - s;
    if (base + 0 <= n) off[base + 0] = excl; excl += v0;
    if (base + 1 <= n) off[base + 1] = excl; excl += v1;
    if (base + 2 <= n) off[base + 2] = excl; excl += v2;
    if (base + 3 <= n) off[base + 3] = excl;
}

__global__ void fill_kernel(const int* __restrict__ V, const int* __restrict__ E,
                            const int* __restrict__ offC, int* __restrict__ curC,
                            int* __restrict__ adjAll, int nnz) {
    int i = blockIdx.x * blockDim.x + threadIdx.x;
    if (i < nnz) {
        int e = E[i], v = V[i];
        int pe = offC[e] + atomicAdd(&curC[e], 1);
        adjAll[pe] = v;
        int pv = offC[N_EDGES + v] + atomicAdd(&curC[N_EDGES + v], 1);
        adjAll[pv] = e;
    }
}

// ---------------- phase 1: edge aggregation (one wave per edge, bf16 gather) ----------------

__global__ void edge_agg(const ushort* __restrict__ Xbf, const int* __restrict__ adjAll,
                         const int* __restrict__ offC, const float* __restrict__ degE,
                         ushort* __restrict__ Ye) {
    int gid = blockIdx.x * blockDim.x + threadIdx.x;
    int edge = gid >> 6;
    int lane = gid & 63;
    if (edge >= N_EDGES) return;
    int b = offC[edge], e = offC[edge + 1];
    float a0 = 0.f, a1 = 0.f, a2 = 0.f, a3 = 0.f;
    for (int i = b; i < e; ++i) {
        int v = adjAll[i];
        ushortx4 x = *reinterpret_cast<const ushortx4*>(Xbf + (size_t)v * D + lane * 4);
        a0 += bf2f(x[0]); a1 += bf2f(x[1]); a2 += bf2f(x[2]); a3 += bf2f(x[3]);
    }
    int cnt = e - b;
    float s = degE[edge] / (float)(cnt > 1 ? cnt : 1);
    ushortx4 o;
    o[0] = f2bf(a0 * s); o[1] = f2bf(a1 * s); o[2] = f2bf(a2 * s); o[3] = f2bf(a3 * s);
    *reinterpret_cast<ushortx4*>(Ye + (size_t)edge * D + lane * 4) = o;
}

// ---------------- phase 2: MFMA GEMM  Ze[MP,256] = Ye[MP,256] @ W  (bf16, LDS-free) ----------------

__global__ void __launch_bounds__(256) gemm_mfma(const ushort* __restrict__ A,
                                                 const ushort* __restrict__ WT,
                                                 ushort* __restrict__ C, int M) {
    int wid  = threadIdx.x >> 6;
    int lane = threadIdx.x & 63;
    int row0 = blockIdx.x * 64 + wid * 16;
    int lr  = lane & 15;
    int lk8 = (lane >> 4) * 8;
    f32x4 acc[16];
#pragma unroll
    for (int t = 0; t < 16; ++t) acc[t] = (f32x4){0.f, 0.f, 0.f, 0.f};
    int arow = row0 + lr;
    if (arow >= M) arow = M - 1;                      // clamp: load-safe, store guarded
    const ushort* aptr = A + (size_t)arow * D;
#pragma unroll
    for (int k0 = 0; k0 < D; k0 += 32) {
        short8 af = *reinterpret_cast<const short8*>(aptr + k0 + lk8);
#pragma unroll
        for (int t = 0; t < 16; ++t) {
            short8 bf = *reinterpret_cast<const short8*>(
                WT + (size_t)(t * 16 + lr) * D + k0 + lk8);
            acc[t] = __builtin_amdgcn_mfma_f32_16x16x32_bf16(af, bf, acc[t], 0, 0, 0);
        }
    }
    int crow = row0 + (lane >> 4) * 4;                // C/D: col=lane&15, row=(lane>>4)*4+reg
#pragma unroll
    for (int t = 0; t < 16; ++t) {
        int ccol = t * 16 + lr;
#pragma unroll
        for (int r = 0; r < 4; ++r) {
            int rr = crow + r;
            if (rr < M) C[(size_t)rr * D + ccol] = f2bf(acc[t][r]);
        }
    }
}

// ---------------- phase 3: node aggregation (one wave per node, bf16 gather) ----------------

__global__ void node_agg(const ushort* __restrict__ Ze, const int* __restrict__ adjAll,
                         const int* __restrict__ offC, const float* __restrict__ degV,
                         const float* __restrict__ bias, float* __restrict__ out) {
    int gid = blockIdx.x * blockDim.x + threadIdx.x;
    int node = gid >> 6;
    int lane = gid & 63;
    if (node >= N_NODES) return;
    int b = offC[N_EDGES + node], e = offC[N_EDGES + node + 1];
    float a0 = 0.f, a1 = 0.f, a2 = 0.f, a3 = 0.f;
    for (int i = b; i < e; ++i) {
        int ed = adjAll[i];
        ushortx4 z = *reinterpret_cast<const ushortx4*>(Ze + (size_t)ed * D + lane * 4);
        a0 += bf2f(z[0]); a1 += bf2f(z[1]); a2 += bf2f(z[2]); a3 += bf2f(z[3]);
    }
    float dv = degV[node];
    float4 b4 = *reinterpret_cast<const float4*>(bias + lane * 4);
    float4 o = {a0 * dv + b4.x, a1 * dv + b4.y, a2 * dv + b4.z, a3 * dv + b4.w};
    *reinterpret_cast<float4*>(out + (size_t)node * D + lane * 4) = o;
}

// ---------------- launch ----------------

extern "C" void kernel_launch(void* const* d_in, const int* in_sizes, int n_in,
                              void* d_out, int out_size, void* d_ws, size_t ws_size,
                              hipStream_t stream) {
    const float* input  = (const float*)d_in[0];
    const int*   V      = (const int*)d_in[1];
    const int*   E      = (const int*)d_in[2];
    const float* degV   = (const float*)d_in[3];
    const float* degE   = (const float*)d_in[4];
    const float* weight = (const float*)d_in[5];
    const float* bias   = (const float*)d_in[6];
    float* out = (float*)d_out;

    int* cntC   = (int*)d_ws;                       // NTOT
    int* curC   = cntC + NTOT;                      // NTOT
    int* offC   = curC + NTOT;                      // NTOT+1
    int* bsum   = offC + (NTOT + 1);                // 128
    int* adjAll = bsum + 128;                       // 2*NNZ
    uintptr_t p = (uintptr_t)(adjAll + 2 * NNZ_);
    p = (p + 255) & ~(uintptr_t)255;
    ushort* Xbf = (ushort*)p;                       // N_NODES*D   (51.2 MB)
    ushort* Ye  = Xbf + (size_t)N_NODES * D;        // MP*D        (12.8 MB)
    ushort* Ze  = Ye + (size_t)MP * D;              // MP*D        (12.8 MB)
    ushort* WT  = Ze + (size_t)MP * D;              // 256*256     (128 KB)

    hipMemsetAsync(cntC, 0, (size_t)(2 * NTOT) * sizeof(int), stream);

    cvt_in<<<(N_NODES * D / 8 + 255) / 256, 256, 0, stream>>>(input, Xbf, N_NODES * D / 8);
    cvt_wt<<<256, 256, 0, stream>>>(weight, WT);

    hist_kernel<<<(NNZ_ + 255) / 256, 256, 0, stream>>>(V, E, cntC, NNZ_);
    scan_bsum<<<NBLK, 256, 0, stream>>>(cntC, bsum, NTOT);
    scan_boff<<<1, 128, 0, stream>>>(bsum, NBLK);
    scan_write<<<NBLK, 256, 0, stream>>>(cntC, bsum, offC, NTOT);
    fill_kernel<<<(NNZ_ + 255) / 256, 256, 0, stream>>>(V, E, offC, curC, adjAll, NNZ_);

    edge_agg<<<(N_EDGES * 64 + 255) / 256, 256, 0, stream>>>(Xbf, adjAll, offC, degE, Ye);

    gemm_mfma<<<MP / 64, 256, 0, stream>>>(Ye, WT, Ze, N_EDGES);

    node_agg<<<(N_NODES * 64 + 255) / 256, 256, 0, stream>>>(Ze, adjAll, offC, degV, bias, out);
}